// Round 5
// baseline (4859.526 us; speedup 1.0000x reference)
//
#include <hip/hip_runtime.h>
#include <hip/hip_bf16.h>
#include <math.h>

#define N_NODES 50000
#define N_EDGES 800000
#define N_GRAPHS 1024
#define HD 128
#define NLAYERS 5
#define EDGE_IN 41
#define NT 3
#define LN_EPS 1e-5f

typedef unsigned int uint;
typedef unsigned short ushort;
typedef __attribute__((ext_vector_type(8))) short short8;
typedef __attribute__((ext_vector_type(16))) float f32x16;

// fast silu: x * rcp(1+exp(-x)); v_rcp_f32 rel err ~1e-7 (vs 6.8e-4 threshold)
__device__ __forceinline__ float silu_f(float v) {
    return v * __builtin_amdgcn_rcpf(1.0f + __expf(-v));
}

// round-to-nearest-even f32 -> bf16 bits
__device__ __forceinline__ ushort f2bf(float f) {
    uint u = __float_as_uint(f);
    u = u + 0x7FFFu + ((u >> 16) & 1u);
    return (ushort)(u >> 16);
}

__device__ __forceinline__ short8 ld16(const ushort* p) {
    union { int4 i; short8 s; } u;
    u.i = *(const int4*)p;
    return u.s;
}

__device__ __forceinline__ f32x16 mfma32(short8 a, short8 b, f32x16 c) {
    return __builtin_amdgcn_mfma_f32_32x32x16_bf16(a, b, c, 0, 0, 0);
}

// ---------------- zero ----------------
__global__ void k_zero(float* __restrict__ p, int n) {
    int i = blockIdx.x * 256 + threadIdx.x;
    if (i < n) p[i] = 0.0f;
}

// ---------------- weight swizzle (t-major fragment order) ----------------
// element ((t*16+s)*64+L)*8+j  <-  W[k = s*16 + (L>>5)*8 + j][n = t*32 + (L&31)]
__global__ void k_swz_w1(const float* __restrict__ w1, ushort* __restrict__ w1s) {
    int i = blockIdx.x * 256 + threadIdx.x;            // 5 * 65536
    int l = i >> 16;
    int r = i & 65535;
    int j = r & 7, L = (r >> 3) & 63, s = (r >> 9) & 15, t = (r >> 13) & 7;
    int k = s * 16 + (L >> 5) * 8 + j;
    int n = t * 32 + (L & 31);
    w1s[i] = f2bf(w1[(size_t)l * 65536 + k * 256 + n]);
}
__global__ void k_swz_w2(const float* __restrict__ w2, ushort* __restrict__ w2s) {
    int i = blockIdx.x * 256 + threadIdx.x;            // 5 * 32768
    int l = i >> 15;
    int r = i & 32767;
    int j = r & 7, L = (r >> 3) & 63, s = (r >> 9) & 15, t = (r >> 13) & 3;
    int k = s * 16 + (L >> 5) * 8 + j;
    int n = t * 32 + (L & 31);
    w2s[i] = f2bf(w2[(size_t)l * 32768 + k * 128 + n]);
}

// ---------------- node embed: x = silu(LN(atom @ emb_w + emb_b)) ----------------
__global__ __launch_bounds__(128) void k_node_embed(
    const float* __restrict__ atom, const float* __restrict__ w,
    const float* __restrict__ b, const float* __restrict__ g,
    const float* __restrict__ bet, float* __restrict__ x, ushort* __restrict__ x_bf)
{
    int node = blockIdx.x;
    int h = threadIdx.x;
    float4 a = *(const float4*)(atom + (size_t)node * 4);
    float acc = b[h] + a.x * w[h] + a.y * w[HD + h] + a.z * w[2 * HD + h] + a.w * w[3 * HD + h];
    __shared__ float s1[2], s2[2];
    float sum = acc, sq = acc * acc;
    for (int off = 32; off > 0; off >>= 1) { sum += __shfl_down(sum, off); sq += __shfl_down(sq, off); }
    int wid = h >> 6, lane = h & 63;
    if (lane == 0) { s1[wid] = sum; s2[wid] = sq; }
    __syncthreads();
    float m = (s1[0] + s1[1]) * (1.0f / 128.0f);
    float v = (s2[0] + s2[1]) * (1.0f / 128.0f) - m * m;
    float y = (acc - m) * rsqrtf(v + LN_EPS) * g[h] + bet[h];
    y = silu_f(y);
    x[(size_t)node * HD + h] = y;
    x_bf[(size_t)node * HD + h] = f2bf(y);
}

// ---------------- edge embed -> bf16 ----------------
#define ETILE 32
__global__ __launch_bounds__(128) void k_edge_embed(
    const float* __restrict__ fea, const float* __restrict__ w,
    const float* __restrict__ b, ushort* __restrict__ e_bf)
{
    __shared__ float sf[ETILE][EDGE_IN + 1];
    int e0 = blockIdx.x * ETILE;
    int tid = threadIdx.x;
    for (int i = tid; i < ETILE * EDGE_IN; i += 128) {
        int m = i / EDGE_IN, k = i % EDGE_IN;
        sf[m][k] = fea[(size_t)(e0 + m) * EDGE_IN + k];
    }
    __syncthreads();
    float bb = b[tid];
    float acc[ETILE];
#pragma unroll
    for (int m = 0; m < ETILE; m++) acc[m] = bb;
    for (int k = 0; k < EDGE_IN; k++) {
        float wk = w[k * HD + tid];
#pragma unroll
        for (int m = 0; m < ETILE; m++) acc[m] += sf[m][k] * wk;
    }
#pragma unroll
    for (int m = 0; m < ETILE; m++)
        e_bf[(size_t)(e0 + m) * HD + tid] = f2bf(silu_f(acc[m]));
}

// ---------------- degree / graph counts ----------------
__global__ void k_count(const int* __restrict__ nbr_idx, float* __restrict__ cnt) {
    int i = blockIdx.x * 256 + threadIdx.x;
    if (i < N_EDGES) atomicAdd(&cnt[nbr_idx[2 * i + 1]], 1.0f);
}
__global__ void k_gcount(const int* __restrict__ bm, float* __restrict__ gcnt) {
    int i = blockIdx.x * 256 + threadIdx.x;
    if (i < N_NODES) atomicAdd(&gcnt[bm[i]], 1.0f);
}

// ---------------- fused conv layer (MFMA bf16, chunk-interleaved, tiny LDS) ----------------
// 1 wave per block, 32 edges per wave. 8 passes of 32 GEMM1 output cols:
//   pass t: acc1[16] = concat(x[src],e) @ W1[:, t*32:+32]   (16 MFMAs)
//           silu -> bf16 chunk in LDS (32x32, pitch 40)
//           GEMM2 partial: k-steps ss=2t,2t+1 into acc2[4][16] (8 MFMAs)
// Epilogue: silu + coalesced atomicAdd into aggr[dst].
// LDS ~2.7 KB (occupancy VGPR-capped at 4 waves/SIMD, not LDS-capped).
#define M1CP 40   // chunk pitch (bf16): 80 B rows, 16B-aligned frag reads
__global__ __launch_bounds__(64, 4) void k_conv_mfma(
    const ushort* __restrict__ x_bf, const ushort* __restrict__ e_bf,
    const int* __restrict__ nbr_idx,
    const ushort* __restrict__ w1s, const float* __restrict__ b1,
    const ushort* __restrict__ w2s, const float* __restrict__ b2,
    float* __restrict__ aggr)
{
    __shared__ __align__(16) ushort sM1c[32 * M1CP];
    __shared__ int sDst[32];

    int L = threadIdx.x;
    int l31 = L & 31, lhi = L >> 5;
    int e0 = blockIdx.x * 32;

    if (L < 32) sDst[L] = nbr_idx[2 * (e0 + L) + 1];
    int src = nbr_idx[2 * (e0 + l31)];
    const ushort* xb = x_bf + (size_t)src * HD + lhi * 8;
    const ushort* ep = e_bf + (size_t)(e0 + l31) * HD + lhi * 8;
    __syncthreads();

    f32x16 acc2[4];
#pragma unroll
    for (int t = 0; t < 4; ++t)
#pragma unroll
        for (int i = 0; i < 16; ++i) acc2[t][i] = 0.0f;

    for (int t = 0; t < 8; ++t) {
        // ---- GEMM1 pass: 32 output cols ----
        f32x16 a1;
#pragma unroll
        for (int i = 0; i < 16; ++i) a1[i] = 0.0f;
        const ushort* wb = w1s + t * 8192 + (size_t)L * 8;
#pragma unroll
        for (int s = 0; s < 8; ++s)
            a1 = mfma32(ld16(xb + s * 16), ld16(wb + s * 512), a1);
#pragma unroll
        for (int s = 0; s < 8; ++s)
            a1 = mfma32(ld16(ep + s * 16), ld16(wb + 4096 + s * 512), a1);

        // ---- bias + silu -> bf16 chunk in LDS ----
        float bv = b1[t * 32 + l31];
        ushort* mcol = sM1c + l31;
#pragma unroll
        for (int r = 0; r < 16; ++r) {
            int row = (r & 3) + ((r >> 2) << 3) + (lhi << 2);
            mcol[row * M1CP] = f2bf(silu_f(a1[r] + bv));
        }
        __syncthreads();

        // ---- GEMM2 partial: global k-steps 2t, 2t+1 ----
        const ushort* arow = sM1c + l31 * M1CP + lhi * 8;
#pragma unroll
        for (int ssl = 0; ssl < 2; ++ssl) {
            short8 af = ld16(arow + ssl * 16);
            int ss = 2 * t + ssl;
#pragma unroll
            for (int tt = 0; tt < 4; ++tt) {
                short8 bf = ld16(w2s + (((tt * 16 + ss) * 64 + L) << 3));
                acc2[tt] = mfma32(af, bf, acc2[tt]);
            }
        }
        __syncthreads();   // protect chunk reuse (WAR) across passes
    }

    // ---- epilogue: bias + silu + coalesced atomic scatter ----
    int dstv[16];
#pragma unroll
    for (int r = 0; r < 16; ++r)
        dstv[r] = sDst[(r & 3) + ((r >> 2) << 3) + (lhi << 2)];
#pragma unroll
    for (int tt = 0; tt < 4; ++tt) {
        float bv = b2[tt * 32 + l31];
#pragma unroll
        for (int r = 0; r < 16; ++r)
            atomicAdd(aggr + (size_t)dstv[r] * HD + tt * 32 + l31, silu_f(acc2[tt][r] + bv));
    }
}

// ---------------- post: x = LN(x + aggr/cnt); emit bf16 ----------------
__global__ __launch_bounds__(128) void k_post(
    const float* __restrict__ aggr, const float* __restrict__ cnt,
    const float* __restrict__ g, const float* __restrict__ bet,
    float* __restrict__ x, ushort* __restrict__ x_bf)
{
    int node = blockIdx.x;
    int h = threadIdx.x;
    float inv = __builtin_amdgcn_rcpf(fmaxf(cnt[node], 1.0f));
    float acc = x[(size_t)node * HD + h] + aggr[(size_t)node * HD + h] * inv;
    __shared__ float s1[2], s2[2];
    float sum = acc, sq = acc * acc;
    for (int off = 32; off > 0; off >>= 1) { sum += __shfl_down(sum, off); sq += __shfl_down(sq, off); }
    int wid = h >> 6, lane = h & 63;
    if (lane == 0) { s1[wid] = sum; s2[wid] = sq; }
    __syncthreads();
    float m = (s1[0] + s1[1]) * (1.0f / 128.0f);
    float v = (s2[0] + s2[1]) * (1.0f / 128.0f) - m * m;
    float y = (acc - m) * rsqrtf(v + LN_EPS) * g[h] + bet[h];
    x[(size_t)node * HD + h] = y;
    x_bf[(size_t)node * HD + h] = f2bf(y);
}

// ---------------- graph pooling ----------------
__global__ __launch_bounds__(128) void k_gaggr(
    const float* __restrict__ x, const int* __restrict__ bm,
    float* __restrict__ crystal)
{
    int node = blockIdx.x;
    int h = threadIdx.x;
    atomicAdd(&crystal[(size_t)bm[node] * HD + h], x[(size_t)node * HD + h]);
}

// ---------------- readout MLP ----------------
__global__ __launch_bounds__(128) void k_readout(
    const float* __restrict__ crystal, const float* __restrict__ gcnt,
    const float* __restrict__ w1, const float* __restrict__ b1,
    const float* __restrict__ w2, const float* __restrict__ b2,
    const float* __restrict__ w3, const float* __restrict__ b3,
    float* __restrict__ out)
{
    int gph = blockIdx.x;
    int t = threadIdx.x;
    __shared__ float sc[HD], sh1[HD], sh2[64];
    float inv = __builtin_amdgcn_rcpf(fmaxf(gcnt[gph], 1.0f));
    sc[t] = crystal[(size_t)gph * HD + t] * inv;
    __syncthreads();
    float acc = b1[t];
    for (int k = 0; k < HD; k++) acc += sc[k] * w1[k * HD + t];
    sh1[t] = silu_f(acc);
    __syncthreads();
    if (t < 64) {
        float a2 = b2[t];
        for (int k = 0; k < HD; k++) a2 += sh1[k] * w2[k * 64 + t];
        sh2[t] = silu_f(a2);
    }
    __syncthreads();
    if (t < NT) {
        float a3 = b3[t];
        for (int k = 0; k < 64; k++) a3 += sh2[k] * w3[k * NT + t];
        out[(size_t)gph * NT + t] = a3;
    }
}

extern "C" void kernel_launch(void* const* d_in, const int* in_sizes, int n_in,
                              void* d_out, int out_size, void* d_ws, size_t ws_size,
                              hipStream_t stream)
{
    const float* atom_fea = (const float*)d_in[0];
    const float* nbr_fea  = (const float*)d_in[1];
    const int*   nbr_idx  = (const int*)d_in[2];
    const int*   bm       = (const int*)d_in[3];
    const float* emb_w    = (const float*)d_in[4];
    const float* emb_b    = (const float*)d_in[5];
    const float* emb_ln_g = (const float*)d_in[6];
    const float* emb_ln_b = (const float*)d_in[7];
    const float* edge_w   = (const float*)d_in[8];
    const float* edge_b   = (const float*)d_in[9];
    const float* conv_w1  = (const float*)d_in[10];
    const float* conv_b1  = (const float*)d_in[11];
    const float* conv_w2  = (const float*)d_in[12];
    const float* conv_b2  = (const float*)d_in[13];
    const float* ln_g     = (const float*)d_in[14];
    const float* ln_b     = (const float*)d_in[15];
    const float* out_w1   = (const float*)d_in[16];
    const float* out_b1   = (const float*)d_in[17];
    const float* out_w2   = (const float*)d_in[18];
    const float* out_b2   = (const float*)d_in[19];
    const float* out_w3   = (const float*)d_in[20];
    const float* out_b3   = (const float*)d_in[21];
    float* out = (float*)d_out;

    // ---- workspace layout (256B-aligned regions) ----
    char* base = (char*)d_ws;
    size_t off = 0;
    auto alloc = [&](size_t bytes) -> char* {
        char* p = base + off;
        off = (off + bytes + 255) & ~(size_t)255;
        return p;
    };
    float*  xbuf    = (float*) alloc((size_t)N_NODES * HD * 4);
    float*  aggr    = (float*) alloc((size_t)N_NODES * HD * 4);
    float*  cnt     = (float*) alloc((size_t)N_NODES * 4);
    float*  crystal = (float*) alloc((size_t)N_GRAPHS * HD * 4);
    float*  gcnt    = (float*) alloc((size_t)N_GRAPHS * 4);
    ushort* x_bf    = (ushort*)alloc((size_t)N_NODES * HD * 2);
    ushort* e_bf    = (ushort*)alloc((size_t)N_EDGES * HD * 2);
    ushort* w1s     = (ushort*)alloc((size_t)NLAYERS * 65536 * 2);
    ushort* w2s     = (ushort*)alloc((size_t)NLAYERS * 32768 * 2);

    // weights -> swizzled bf16
    k_swz_w1<<<(NLAYERS * 65536) / 256, 256, 0, stream>>>(conv_w1, w1s);
    k_swz_w2<<<(NLAYERS * 32768) / 256, 256, 0, stream>>>(conv_w2, w2s);

    // zero cnt + crystal + gcnt (contiguous region)
    int zn = N_NODES + N_GRAPHS * HD + N_GRAPHS + 128;
    k_zero<<<(zn + 255) / 256, 256, 0, stream>>>(cnt, zn);

    k_node_embed<<<N_NODES, 128, 0, stream>>>(atom_fea, emb_w, emb_b, emb_ln_g, emb_ln_b, xbuf, x_bf);
    k_edge_embed<<<N_EDGES / ETILE, 128, 0, stream>>>(nbr_fea, edge_w, edge_b, e_bf);
    k_count<<<N_EDGES / 256, 256, 0, stream>>>(nbr_idx, cnt);
    k_gcount<<<(N_NODES + 255) / 256, 256, 0, stream>>>(bm, gcnt);

    for (int l = 0; l < NLAYERS; ++l) {
        k_zero<<<(N_NODES * HD) / 256, 256, 0, stream>>>(aggr, N_NODES * HD);
        k_conv_mfma<<<N_EDGES / 32, 64, 0, stream>>>(
            x_bf, e_bf, nbr_idx,
            w1s + (size_t)l * 65536, conv_b1 + (size_t)l * 256,
            w2s + (size_t)l * 32768, conv_b2 + (size_t)l * 128,
            aggr);
        k_post<<<N_NODES, 128, 0, stream>>>(aggr, cnt, ln_g + (size_t)l * HD, ln_b + (size_t)l * HD, xbuf, x_bf);
    }

    k_gaggr<<<N_NODES, 128, 0, stream>>>(xbuf, bm, crystal);
    k_readout<<<N_GRAPHS, 128, 0, stream>>>(crystal, gcnt, out_w1, out_b1, out_w2, out_b2, out_w3, out_b3, out);
}

// Round 6
// 3387.124 us; speedup vs baseline: 1.4347x; 1.4347x over previous
//
#include <hip/hip_runtime.h>
#include <hip/hip_bf16.h>
#include <math.h>

#define N_NODES 50000
#define N_EDGES 800000
#define N_GRAPHS 1024
#define HD 128
#define NLAYERS 5
#define EDGE_IN 41
#define NT 3
#define LN_EPS 1e-5f

typedef unsigned int uint;
typedef unsigned short ushort;
typedef __attribute__((ext_vector_type(8))) short short8;
typedef __attribute__((ext_vector_type(4))) float f32x4;

// fast silu: x * rcp(1+exp(-x)); v_rcp_f32 rel err ~1e-7 (vs 6.8e-4 threshold)
__device__ __forceinline__ float silu_f(float v) {
    return v * __builtin_amdgcn_rcpf(1.0f + __expf(-v));
}

// round-to-nearest-even f32 -> bf16 bits
__device__ __forceinline__ ushort f2bf(float f) {
    uint u = __float_as_uint(f);
    u = u + 0x7FFFu + ((u >> 16) & 1u);
    return (ushort)(u >> 16);
}

__device__ __forceinline__ short8 ld16(const ushort* p) {
    union { int4 i; short8 s; } u;
    u.i = *(const int4*)p;
    return u.s;
}

__device__ __forceinline__ f32x4 mfma16(short8 a, short8 b, f32x4 c) {
    return __builtin_amdgcn_mfma_f32_16x16x32_bf16(a, b, c, 0, 0, 0);
}

// wave-local LDS fence: order + complete ds ops without s_barrier / vmcnt drain
__device__ __forceinline__ void wave_lds_fence() {
    __asm__ volatile("s_waitcnt lgkmcnt(0)" ::: "memory");
}

// ---------------- zero ----------------
__global__ void k_zero(float* __restrict__ p, int n) {
    int i = blockIdx.x * 256 + threadIdx.x;
    if (i < n) p[i] = 0.0f;
}

// ---------------- weight swizzle: 16x16x32 B-fragment order ----------------
// w1s idx = (((c*8 + s)*64 + L)*8 + j  <-  W1[k = 32s + (L>>4)*8 + j][n = 16c + (L&15)]
__global__ void k_swz_w1(const float* __restrict__ w1, ushort* __restrict__ w1s) {
    int i = blockIdx.x * 256 + threadIdx.x;            // 5 * 65536
    int l = i >> 16;
    int r = i & 65535;
    int j = r & 7, L = (r >> 3) & 63, s = (r >> 9) & 7, c = (r >> 12) & 15;
    int k = 32 * s + ((L >> 4) & 3) * 8 + j;
    int n = 16 * c + (L & 15);
    w1s[i] = f2bf(w1[(size_t)l * 65536 + k * 256 + n]);
}
// w2s idx = ((s2*8 + t)*64 + L)*8 + j  <-  W2[k = 32*s2 + (L>>4)*8 + j][n = 16t + (L&15)]
__global__ void k_swz_w2(const float* __restrict__ w2, ushort* __restrict__ w2s) {
    int i = blockIdx.x * 256 + threadIdx.x;            // 5 * 32768
    int l = i >> 15;
    int r = i & 32767;
    int j = r & 7, L = (r >> 3) & 63, t = (r >> 9) & 7, s2 = (r >> 12) & 7;
    int k = 32 * s2 + ((L >> 4) & 3) * 8 + j;
    int n = 16 * t + (L & 15);
    w2s[i] = f2bf(w2[(size_t)l * 32768 + k * 128 + n]);
}

// ---------------- node embed: x = silu(LN(atom @ emb_w + emb_b)) ----------------
__global__ __launch_bounds__(128) void k_node_embed(
    const float* __restrict__ atom, const float* __restrict__ w,
    const float* __restrict__ b, const float* __restrict__ g,
    const float* __restrict__ bet, float* __restrict__ x, ushort* __restrict__ x_bf)
{
    int node = blockIdx.x;
    int h = threadIdx.x;
    float4 a = *(const float4*)(atom + (size_t)node * 4);
    float acc = b[h] + a.x * w[h] + a.y * w[HD + h] + a.z * w[2 * HD + h] + a.w * w[3 * HD + h];
    __shared__ float s1[2], s2[2];
    float sum = acc, sq = acc * acc;
    for (int off = 32; off > 0; off >>= 1) { sum += __shfl_down(sum, off); sq += __shfl_down(sq, off); }
    int wid = h >> 6, lane = h & 63;
    if (lane == 0) { s1[wid] = sum; s2[wid] = sq; }
    __syncthreads();
    float m = (s1[0] + s1[1]) * (1.0f / 128.0f);
    float v = (s2[0] + s2[1]) * (1.0f / 128.0f) - m * m;
    float y = (acc - m) * rsqrtf(v + LN_EPS) * g[h] + bet[h];
    y = silu_f(y);
    x[(size_t)node * HD + h] = y;
    x_bf[(size_t)node * HD + h] = f2bf(y);
}

// ---------------- edge embed -> bf16 ----------------
#define ETILE 32
__global__ __launch_bounds__(128) void k_edge_embed(
    const float* __restrict__ fea, const float* __restrict__ w,
    const float* __restrict__ b, ushort* __restrict__ e_bf)
{
    __shared__ float sf[ETILE][EDGE_IN + 1];
    int e0 = blockIdx.x * ETILE;
    int tid = threadIdx.x;
    for (int i = tid; i < ETILE * EDGE_IN; i += 128) {
        int m = i / EDGE_IN, k = i % EDGE_IN;
        sf[m][k] = fea[(size_t)(e0 + m) * EDGE_IN + k];
    }
    __syncthreads();
    float bb = b[tid];
    float acc[ETILE];
#pragma unroll
    for (int m = 0; m < ETILE; m++) acc[m] = bb;
    for (int k = 0; k < EDGE_IN; k++) {
        float wk = w[k * HD + tid];
#pragma unroll
        for (int m = 0; m < ETILE; m++) acc[m] += sf[m][k] * wk;
    }
#pragma unroll
    for (int m = 0; m < ETILE; m++)
        e_bf[(size_t)(e0 + m) * HD + tid] = f2bf(silu_f(acc[m]));
}

// ---------------- degree / graph counts ----------------
__global__ void k_count(const int* __restrict__ nbr_idx, float* __restrict__ cnt) {
    int i = blockIdx.x * 256 + threadIdx.x;
    if (i < N_EDGES) atomicAdd(&cnt[nbr_idx[2 * i + 1]], 1.0f);
}
__global__ void k_gcount(const int* __restrict__ bm, float* __restrict__ gcnt) {
    int i = blockIdx.x * 256 + threadIdx.x;
    if (i < N_NODES) atomicAdd(&gcnt[bm[i]], 1.0f);
}

// ---------------- fused conv layer: 16x16x32 MFMA, 16 edges/wave ----------------
// A-frags (concat(x[src],e), 256 k) loaded ONCE into 32 VGPRs.
// 8 passes: GEMM1 computes 32 m1-cols (2 chunks, 16 MFMAs, acc 8 regs),
//   silu->bf16 -> wave-private LDS chunk (16x32, pitch 40),
//   GEMM2 k-step vs those 32 k (8 MFMAs into acc2[8] = 32 regs).
// Wave-local lgkmcnt fences only (no s_barrier -> weight prefetch survives).
// 4 waves/block for L1 weight co-streaming.
#define M1CP 40
__global__ __launch_bounds__(256, 4) void k_conv_mfma(
    const ushort* __restrict__ x_bf, const ushort* __restrict__ e_bf,
    const int* __restrict__ nbr_idx,
    const ushort* __restrict__ w1s, const float* __restrict__ cb1,
    const ushort* __restrict__ w2s, const float* __restrict__ cb2,
    float* __restrict__ aggr)
{
    __shared__ __align__(16) ushort sM1[4][16 * M1CP];
    __shared__ int sDst[64];

    int tid = threadIdx.x;
    int w = tid >> 6;
    int L = tid & 63;
    int m = L & 15;          // edge within tile
    int quad = L >> 4;       // 0..3
    int e0 = blockIdx.x * 64 + w * 16;

    if (L < 16) sDst[w * 16 + L] = nbr_idx[2 * (e0 + L) + 1];
    int src = nbr_idx[2 * (e0 + m)];

    // A-fragments, loaded once: s=0..3 from x[src], s=4..7 from e
    const ushort* xr = x_bf + (size_t)src * HD + quad * 8;
    const ushort* er = e_bf + (size_t)(e0 + m) * HD + quad * 8;
    short8 af[8];
#pragma unroll
    for (int s = 0; s < 4; ++s) af[s] = ld16(xr + 32 * s);
#pragma unroll
    for (int s = 0; s < 4; ++s) af[4 + s] = ld16(er + 32 * s);

    f32x4 acc2[8];
#pragma unroll
    for (int t = 0; t < 8; ++t)
#pragma unroll
        for (int r = 0; r < 4; ++r) acc2[t][r] = 0.0f;

    ushort* sm = sM1[w];

    for (int c2 = 0; c2 < 8; ++c2) {
        // ---- GEMM1: col chunks 2*c2, 2*c2+1 ----
        f32x4 p0, p1;
#pragma unroll
        for (int r = 0; r < 4; ++r) { p0[r] = 0.0f; p1[r] = 0.0f; }
        const ushort* wb = w1s + c2 * 8192 + (size_t)L * 8;
#pragma unroll
        for (int s = 0; s < 8; ++s) {
            short8 wv0 = ld16(wb + s * 512);
            short8 wv1 = ld16(wb + 4096 + s * 512);
            p0 = mfma16(af[s], wv0, p0);
            p1 = mfma16(af[s], wv1, p1);
        }

        // ---- bias + silu -> bf16 chunk (rows=edges, 32 cols) ----
        float bva = cb1[c2 * 32 + m];
        float bvb = cb1[c2 * 32 + 16 + m];
#pragma unroll
        for (int r = 0; r < 4; ++r) {
            int row = quad * 4 + r;
            sm[row * M1CP + m]      = f2bf(silu_f(p0[r] + bva));
            sm[row * M1CP + 16 + m] = f2bf(silu_f(p1[r] + bvb));
        }
        wave_lds_fence();

        // ---- GEMM2 k-step c2 (k = 32*c2..+31) ----
        short8 a2 = ld16(sm + m * M1CP + quad * 8);
        const ushort* wb2 = w2s + c2 * 4096 + (size_t)L * 8;
#pragma unroll
        for (int t = 0; t < 8; ++t)
            acc2[t] = mfma16(a2, ld16(wb2 + t * 512), acc2[t]);
        wave_lds_fence();   // WAR: chunk reused next pass
    }

    // ---- epilogue: bias + silu + coalesced atomic scatter ----
#pragma unroll
    for (int t = 0; t < 8; ++t) {
        float bv = cb2[t * 16 + m];
#pragma unroll
        for (int r = 0; r < 4; ++r) {
            int dst = sDst[w * 16 + quad * 4 + r];
            atomicAdd(aggr + (size_t)dst * HD + t * 16 + m, silu_f(acc2[t][r] + bv));
        }
    }
}

// ---------------- post: x = LN(x + aggr/cnt); emit bf16 ----------------
__global__ __launch_bounds__(128) void k_post(
    const float* __restrict__ aggr, const float* __restrict__ cnt,
    const float* __restrict__ g, const float* __restrict__ bet,
    float* __restrict__ x, ushort* __restrict__ x_bf)
{
    int node = blockIdx.x;
    int h = threadIdx.x;
    float inv = __builtin_amdgcn_rcpf(fmaxf(cnt[node], 1.0f));
    float acc = x[(size_t)node * HD + h] + aggr[(size_t)node * HD + h] * inv;
    __shared__ float s1[2], s2[2];
    float sum = acc, sq = acc * acc;
    for (int off = 32; off > 0; off >>= 1) { sum += __shfl_down(sum, off); sq += __shfl_down(sq, off); }
    int wid = h >> 6, lane = h & 63;
    if (lane == 0) { s1[wid] = sum; s2[wid] = sq; }
    __syncthreads();
    float m = (s1[0] + s1[1]) * (1.0f / 128.0f);
    float v = (s2[0] + s2[1]) * (1.0f / 128.0f) - m * m;
    float y = (acc - m) * rsqrtf(v + LN_EPS) * g[h] + bet[h];
    x[(size_t)node * HD + h] = y;
    x_bf[(size_t)node * HD + h] = f2bf(y);
}

// ---------------- graph pooling ----------------
__global__ __launch_bounds__(128) void k_gaggr(
    const float* __restrict__ x, const int* __restrict__ bm,
    float* __restrict__ crystal)
{
    int node = blockIdx.x;
    int h = threadIdx.x;
    atomicAdd(&crystal[(size_t)bm[node] * HD + h], x[(size_t)node * HD + h]);
}

// ---------------- readout MLP ----------------
__global__ __launch_bounds__(128) void k_readout(
    const float* __restrict__ crystal, const float* __restrict__ gcnt,
    const float* __restrict__ w1, const float* __restrict__ b1,
    const float* __restrict__ w2, const float* __restrict__ b2,
    const float* __restrict__ w3, const float* __restrict__ b3,
    float* __restrict__ out)
{
    int gph = blockIdx.x;
    int t = threadIdx.x;
    __shared__ float sc[HD], sh1[HD], sh2[64];
    float inv = __builtin_amdgcn_rcpf(fmaxf(gcnt[gph], 1.0f));
    sc[t] = crystal[(size_t)gph * HD + t] * inv;
    __syncthreads();
    float acc = b1[t];
    for (int k = 0; k < HD; k++) acc += sc[k] * w1[k * HD + t];
    sh1[t] = silu_f(acc);
    __syncthreads();
    if (t < 64) {
        float a2 = b2[t];
        for (int k = 0; k < HD; k++) a2 += sh1[k] * w2[k * 64 + t];
        sh2[t] = silu_f(a2);
    }
    __syncthreads();
    if (t < NT) {
        float a3 = b3[t];
        for (int k = 0; k < 64; k++) a3 += sh2[k] * w3[k * NT + t];
        out[(size_t)gph * NT + t] = a3;
    }
}

extern "C" void kernel_launch(void* const* d_in, const int* in_sizes, int n_in,
                              void* d_out, int out_size, void* d_ws, size_t ws_size,
                              hipStream_t stream)
{
    const float* atom_fea = (const float*)d_in[0];
    const float* nbr_fea  = (const float*)d_in[1];
    const int*   nbr_idx  = (const int*)d_in[2];
    const int*   bm       = (const int*)d_in[3];
    const float* emb_w    = (const float*)d_in[4];
    const float* emb_b    = (const float*)d_in[5];
    const float* emb_ln_g = (const float*)d_in[6];
    const float* emb_ln_b = (const float*)d_in[7];
    const float* edge_w   = (const float*)d_in[8];
    const float* edge_b   = (const float*)d_in[9];
    const float* conv_w1  = (const float*)d_in[10];
    const float* conv_b1  = (const float*)d_in[11];
    const float* conv_w2  = (const float*)d_in[12];
    const float* conv_b2  = (const float*)d_in[13];
    const float* ln_g     = (const float*)d_in[14];
    const float* ln_b     = (const float*)d_in[15];
    const float* out_w1   = (const float*)d_in[16];
    const float* out_b1   = (const float*)d_in[17];
    const float* out_w2   = (const float*)d_in[18];
    const float* out_b2   = (const float*)d_in[19];
    const float* out_w3   = (const float*)d_in[20];
    const float* out_b3   = (const float*)d_in[21];
    float* out = (float*)d_out;

    // ---- workspace layout (256B-aligned regions) ----
    char* base = (char*)d_ws;
    size_t off = 0;
    auto alloc = [&](size_t bytes) -> char* {
        char* p = base + off;
        off = (off + bytes + 255) & ~(size_t)255;
        return p;
    };
    float*  xbuf    = (float*) alloc((size_t)N_NODES * HD * 4);
    float*  aggr    = (float*) alloc((size_t)N_NODES * HD * 4);
    float*  cnt     = (float*) alloc((size_t)N_NODES * 4);
    float*  crystal = (float*) alloc((size_t)N_GRAPHS * HD * 4);
    float*  gcnt    = (float*) alloc((size_t)N_GRAPHS * 4);
    ushort* x_bf    = (ushort*)alloc((size_t)N_NODES * HD * 2);
    ushort* e_bf    = (ushort*)alloc((size_t)N_EDGES * HD * 2);
    ushort* w1s     = (ushort*)alloc((size_t)NLAYERS * 65536 * 2);
    ushort* w2s     = (ushort*)alloc((size_t)NLAYERS * 32768 * 2);

    // weights -> swizzled bf16
    k_swz_w1<<<(NLAYERS * 65536) / 256, 256, 0, stream>>>(conv_w1, w1s);
    k_swz_w2<<<(NLAYERS * 32768) / 256, 256, 0, stream>>>(conv_w2, w2s);

    // zero cnt + crystal + gcnt (contiguous region)
    int zn = N_NODES + N_GRAPHS * HD + N_GRAPHS + 128;
    k_zero<<<(zn + 255) / 256, 256, 0, stream>>>(cnt, zn);

    k_node_embed<<<N_NODES, 128, 0, stream>>>(atom_fea, emb_w, emb_b, emb_ln_g, emb_ln_b, xbuf, x_bf);
    k_edge_embed<<<N_EDGES / ETILE, 128, 0, stream>>>(nbr_fea, edge_w, edge_b, e_bf);
    k_count<<<N_EDGES / 256, 256, 0, stream>>>(nbr_idx, cnt);
    k_gcount<<<(N_NODES + 255) / 256, 256, 0, stream>>>(bm, gcnt);

    for (int l = 0; l < NLAYERS; ++l) {
        k_zero<<<(N_NODES * HD) / 256, 256, 0, stream>>>(aggr, N_NODES * HD);
        k_conv_mfma<<<N_EDGES / 64, 256, 0, stream>>>(
            x_bf, e_bf, nbr_idx,
            w1s + (size_t)l * 65536, conv_b1 + (size_t)l * 256,
            w2s + (size_t)l * 32768, conv_b2 + (size_t)l * 128,
            aggr);
        k_post<<<N_NODES, 128, 0, stream>>>(aggr, cnt, ln_g + (size_t)l * HD, ln_b + (size_t)l * HD, xbuf, x_bf);
    }

    k_gaggr<<<N_NODES, 128, 0, stream>>>(xbuf, bm, crystal);
    k_readout<<<N_GRAPHS, 128, 0, stream>>>(crystal, gcnt, out_w1, out_b1, out_w2, out_b2, out_w3, out_b3, out);
}

// Round 7
// 2793.594 us; speedup vs baseline: 1.7395x; 1.2125x over previous
//
#include <hip/hip_runtime.h>
#include <hip/hip_bf16.h>
#include <math.h>

#define N_NODES 50000
#define N_EDGES 800000
#define N_GRAPHS 1024
#define HD 128
#define NLAYERS 5
#define EDGE_IN 41
#define NT 3
#define LN_EPS 1e-5f

typedef unsigned int uint;
typedef unsigned short ushort;
typedef __attribute__((ext_vector_type(8))) short short8;
typedef __attribute__((ext_vector_type(4))) float f32x4;

// fast silu: x * rcp(1+exp(-x)); v_rcp_f32 rel err ~1e-7 (vs 6.8e-4 threshold)
__device__ __forceinline__ float silu_f(float v) {
    return v * __builtin_amdgcn_rcpf(1.0f + __expf(-v));
}

// round-to-nearest-even f32 -> bf16 bits
__device__ __forceinline__ ushort f2bf(float f) {
    uint u = __float_as_uint(f);
    u = u + 0x7FFFu + ((u >> 16) & 1u);
    return (ushort)(u >> 16);
}

__device__ __forceinline__ short8 ld16(const ushort* p) {
    union { int4 i; short8 s; } u;
    u.i = *(const int4*)p;
    return u.s;
}

__device__ __forceinline__ f32x4 mfma16(short8 a, short8 b, f32x4 c) {
    return __builtin_amdgcn_mfma_f32_16x16x32_bf16(a, b, c, 0, 0, 0);
}

// wave-local LDS fence
__device__ __forceinline__ void wave_lds_fence() {
    __asm__ volatile("s_waitcnt lgkmcnt(0)" ::: "memory");
}

// async global->LDS, 16 B per lane; HW writes lane's data to ldsbase + lane*16
__device__ __forceinline__ void cp16(const ushort* g, ushort* l) {
    __builtin_amdgcn_global_load_lds(
        (const __attribute__((address_space(1))) unsigned int*)g,
        (__attribute__((address_space(3))) unsigned int*)l, 16, 0, 0);
}

// stage 4096 ushorts (8 KB): wave w covers [w*1024, +1024), lane-contig 16 B
__device__ __forceinline__ void stage4k(ushort* lds, const ushort* g, int w, int L) {
#pragma unroll
    for (int i = 0; i < 2; ++i) {
        int f = w * 1024 + i * 512;
        cp16(g + f + L * 8, lds + f);
    }
}

// ---------------- zero ----------------
__global__ void k_zero(float* __restrict__ p, int n) {
    int i = blockIdx.x * 256 + threadIdx.x;
    if (i < n) p[i] = 0.0f;
}

// ---------------- weight swizzle: 16x16x32 B-fragment order ----------------
// w1s idx = ((c*8 + s)*64 + L)*8 + j  <-  W1[k = 32s + (L>>4)*8 + j][n = 16c + (L&15)]
__global__ void k_swz_w1(const float* __restrict__ w1, ushort* __restrict__ w1s) {
    int i = blockIdx.x * 256 + threadIdx.x;            // 5 * 65536
    int l = i >> 16;
    int r = i & 65535;
    int j = r & 7, L = (r >> 3) & 63, s = (r >> 9) & 7, c = (r >> 12) & 15;
    int k = 32 * s + ((L >> 4) & 3) * 8 + j;
    int n = 16 * c + (L & 15);
    w1s[i] = f2bf(w1[(size_t)l * 65536 + k * 256 + n]);
}
// w2s idx = ((s2*8 + t)*64 + L)*8 + j  <-  W2[k = 32*s2 + (L>>4)*8 + j][n = 16t + (L&15)]
__global__ void k_swz_w2(const float* __restrict__ w2, ushort* __restrict__ w2s) {
    int i = blockIdx.x * 256 + threadIdx.x;            // 5 * 32768
    int l = i >> 15;
    int r = i & 32767;
    int j = r & 7, L = (r >> 3) & 63, t = (r >> 9) & 7, s2 = (r >> 12) & 7;
    int k = 32 * s2 + ((L >> 4) & 3) * 8 + j;
    int n = 16 * t + (L & 15);
    w2s[i] = f2bf(w2[(size_t)l * 32768 + k * 128 + n]);
}

// ---------------- node embed: x = silu(LN(atom @ emb_w + emb_b)) ----------------
__global__ __launch_bounds__(128) void k_node_embed(
    const float* __restrict__ atom, const float* __restrict__ w,
    const float* __restrict__ b, const float* __restrict__ g,
    const float* __restrict__ bet, float* __restrict__ x, ushort* __restrict__ x_bf)
{
    int node = blockIdx.x;
    int h = threadIdx.x;
    float4 a = *(const float4*)(atom + (size_t)node * 4);
    float acc = b[h] + a.x * w[h] + a.y * w[HD + h] + a.z * w[2 * HD + h] + a.w * w[3 * HD + h];
    __shared__ float s1[2], s2[2];
    float sum = acc, sq = acc * acc;
    for (int off = 32; off > 0; off >>= 1) { sum += __shfl_down(sum, off); sq += __shfl_down(sq, off); }
    int wid = h >> 6, lane = h & 63;
    if (lane == 0) { s1[wid] = sum; s2[wid] = sq; }
    __syncthreads();
    float m = (s1[0] + s1[1]) * (1.0f / 128.0f);
    float v = (s2[0] + s2[1]) * (1.0f / 128.0f) - m * m;
    float y = (acc - m) * rsqrtf(v + LN_EPS) * g[h] + bet[h];
    y = silu_f(y);
    x[(size_t)node * HD + h] = y;
    x_bf[(size_t)node * HD + h] = f2bf(y);
}

// ---------------- edge embed -> bf16 ----------------
#define ETILE 32
__global__ __launch_bounds__(128) void k_edge_embed(
    const float* __restrict__ fea, const float* __restrict__ w,
    const float* __restrict__ b, ushort* __restrict__ e_bf)
{
    __shared__ float sf[ETILE][EDGE_IN + 1];
    int e0 = blockIdx.x * ETILE;
    int tid = threadIdx.x;
    for (int i = tid; i < ETILE * EDGE_IN; i += 128) {
        int m = i / EDGE_IN, k = i % EDGE_IN;
        sf[m][k] = fea[(size_t)(e0 + m) * EDGE_IN + k];
    }
    __syncthreads();
    float bb = b[tid];
    float acc[ETILE];
#pragma unroll
    for (int m = 0; m < ETILE; m++) acc[m] = bb;
    for (int k = 0; k < EDGE_IN; k++) {
        float wk = w[k * HD + tid];
#pragma unroll
        for (int m = 0; m < ETILE; m++) acc[m] += sf[m][k] * wk;
    }
#pragma unroll
    for (int m = 0; m < ETILE; m++)
        e_bf[(size_t)(e0 + m) * HD + tid] = f2bf(silu_f(acc[m]));
}

// ---------------- degree / graph counts ----------------
__global__ void k_count(const int* __restrict__ nbr_idx, float* __restrict__ cnt) {
    int i = blockIdx.x * 256 + threadIdx.x;
    if (i < N_EDGES) atomicAdd(&cnt[nbr_idx[2 * i + 1]], 1.0f);
}
__global__ void k_gcount(const int* __restrict__ bm, float* __restrict__ gcnt) {
    int i = blockIdx.x * 256 + threadIdx.x;
    if (i < N_NODES) atomicAdd(&gcnt[bm[i]], 1.0f);
}

// ---------------- fused conv layer: weights via LDS (off the TCP pipe) ----------------
// Block = 4 waves, 64 edges (16/wave). 16 passes of 16 GEMM1 cols:
//   W1 chunk (8 KB) double-buffered, staged via global_load_lds each pass.
//   W2 chunk (8 KB) double-buffered per pass-PAIR, prefetched at odd barriers
//     (2-pass lead; never overwrites a half still being read).
//   GEMM1: 8 MFMAs from LDS B-frags -> silu -> bf16 m1 half-chunk (wave-private).
//   Odd passes: GEMM2 k-step (8 MFMAs) from LDS W2 frags into acc2[8] (32 regs).
// Per-wave weight traffic now rides the LDS pipe (128 B/cyc/CU), global weight
// traffic drops to 192 KB/block (2.4 GB/dispatch).
#define M1CP 40
__global__ __launch_bounds__(256) void k_conv_mfma(
    const ushort* __restrict__ x_bf, const ushort* __restrict__ e_bf,
    const int* __restrict__ nbr_idx,
    const ushort* __restrict__ w1s, const float* __restrict__ cb1,
    const ushort* __restrict__ w2s, const float* __restrict__ cb2,
    float* __restrict__ aggr)
{
    __shared__ __align__(16) ushort sW1[2][4096];
    __shared__ __align__(16) ushort sW2[2][4096];
    __shared__ __align__(16) ushort sM1[4][16 * M1CP];
    __shared__ int sDst[64];

    int tid = threadIdx.x;
    int w = tid >> 6;
    int L = tid & 63;
    int m = L & 15;          // edge within tile (GEMM1 C-col = feature uses m too)
    int quad = L >> 4;       // 0..3
    int e0 = blockIdx.x * 64 + w * 16;

    if (L < 16) sDst[w * 16 + L] = nbr_idx[2 * (e0 + L) + 1];
    int src = nbr_idx[2 * (e0 + m)];

    // A-fragments loaded once: s=0..3 from x[src], s=4..7 from e
    const ushort* xr = x_bf + (size_t)src * HD + quad * 8;
    const ushort* er = e_bf + (size_t)(e0 + m) * HD + quad * 8;
    short8 af[8];
#pragma unroll
    for (int s = 0; s < 4; ++s) af[s] = ld16(xr + 32 * s);
#pragma unroll
    for (int s = 0; s < 4; ++s) af[4 + s] = ld16(er + 32 * s);

    f32x4 acc2[8];
#pragma unroll
    for (int t = 0; t < 8; ++t)
#pragma unroll
        for (int r = 0; r < 4; ++r) acc2[t][r] = 0.0f;

    ushort* sm = sM1[w];

    // prologue: stage pass-0 W1 chunk and s2=0 W2 chunk
    stage4k(sW1[0], w1s, w, L);
    stage4k(sW2[0], w2s, w, L);

    for (int p = 0; p < 16; ++p) {
        __syncthreads();   // drains vmcnt -> current buffers ready
        // prefetch (overlaps compute below)
        if (p < 15) stage4k(sW1[(p + 1) & 1], w1s + (p + 1) * 4096, w, L);
        if ((p & 1) && (p >> 1) < 7)
            stage4k(sW2[((p >> 1) + 1) & 1], w2s + ((p >> 1) + 1) * 4096, w, L);

        // ---- GEMM1: cols [p*16, +16) ----
        f32x4 a1;
#pragma unroll
        for (int r = 0; r < 4; ++r) a1[r] = 0.0f;
        const ushort* wb = sW1[p & 1] + L * 8;
#pragma unroll
        for (int s = 0; s < 8; ++s)
            a1 = mfma16(af[s], ld16(wb + s * 512), a1);

        // ---- bias + silu -> bf16 half-chunk (cols (p&1)*16 + m) ----
        float bv = cb1[p * 16 + m];
        int hb = (p & 1) * 16;
#pragma unroll
        for (int r = 0; r < 4; ++r)
            sm[(quad * 4 + r) * M1CP + hb + m] = f2bf(silu_f(a1[r] + bv));

        // ---- odd pass: GEMM2 k-step s2 = p>>1 over the full 32-col chunk ----
        if (p & 1) {
            wave_lds_fence();   // m1 writes (this+prev pass) complete
            short8 a2 = ld16(sm + m * M1CP + quad * 8);
            const ushort* w2p = sW2[(p >> 1) & 1] + L * 8;
#pragma unroll
            for (int t = 0; t < 8; ++t)
                acc2[t] = mfma16(a2, ld16(w2p + t * 512), acc2[t]);
            wave_lds_fence();   // WAR: chunk halves reused next pass-pair
        }
    }

    // ---- epilogue: bias + silu + coalesced atomic scatter ----
#pragma unroll
    for (int t = 0; t < 8; ++t) {
        float bv = cb2[t * 16 + m];
#pragma unroll
        for (int r = 0; r < 4; ++r) {
            int dst = sDst[w * 16 + quad * 4 + r];
            atomicAdd(aggr + (size_t)dst * HD + t * 16 + m, silu_f(acc2[t][r] + bv));
        }
    }
}

// ---------------- post: x = LN(x + aggr/cnt); emit bf16 ----------------
__global__ __launch_bounds__(128) void k_post(
    const float* __restrict__ aggr, const float* __restrict__ cnt,
    const float* __restrict__ g, const float* __restrict__ bet,
    float* __restrict__ x, ushort* __restrict__ x_bf)
{
    int node = blockIdx.x;
    int h = threadIdx.x;
    float inv = __builtin_amdgcn_rcpf(fmaxf(cnt[node], 1.0f));
    float acc = x[(size_t)node * HD + h] + aggr[(size_t)node * HD + h] * inv;
    __shared__ float s1[2], s2[2];
    float sum = acc, sq = acc * acc;
    for (int off = 32; off > 0; off >>= 1) { sum += __shfl_down(sum, off); sq += __shfl_down(sq, off); }
    int wid = h >> 6, lane = h & 63;
    if (lane == 0) { s1[wid] = sum; s2[wid] = sq; }
    __syncthreads();
    float m = (s1[0] + s1[1]) * (1.0f / 128.0f);
    float v = (s2[0] + s2[1]) * (1.0f / 128.0f) - m * m;
    float y = (acc - m) * rsqrtf(v + LN_EPS) * g[h] + bet[h];
    x[(size_t)node * HD + h] = y;
    x_bf[(size_t)node * HD + h] = f2bf(y);
}

// ---------------- graph pooling ----------------
__global__ __launch_bounds__(128) void k_gaggr(
    const float* __restrict__ x, const int* __restrict__ bm,
    float* __restrict__ crystal)
{
    int node = blockIdx.x;
    int h = threadIdx.x;
    atomicAdd(&crystal[(size_t)bm[node] * HD + h], x[(size_t)node * HD + h]);
}

// ---------------- readout MLP ----------------
__global__ __launch_bounds__(128) void k_readout(
    const float* __restrict__ crystal, const float* __restrict__ gcnt,
    const float* __restrict__ w1, const float* __restrict__ b1,
    const float* __restrict__ w2, const float* __restrict__ b2,
    const float* __restrict__ w3, const float* __restrict__ b3,
    float* __restrict__ out)
{
    int gph = blockIdx.x;
    int t = threadIdx.x;
    __shared__ float sc[HD], sh1[HD], sh2[64];
    float inv = __builtin_amdgcn_rcpf(fmaxf(gcnt[gph], 1.0f));
    sc[t] = crystal[(size_t)gph * HD + t] * inv;
    __syncthreads();
    float acc = b1[t];
    for (int k = 0; k < HD; k++) acc += sc[k] * w1[k * HD + t];
    sh1[t] = silu_f(acc);
    __syncthreads();
    if (t < 64) {
        float a2 = b2[t];
        for (int k = 0; k < HD; k++) a2 += sh1[k] * w2[k * 64 + t];
        sh2[t] = silu_f(a2);
    }
    __syncthreads();
    if (t < NT) {
        float a3 = b3[t];
        for (int k = 0; k < 64; k++) a3 += sh2[k] * w3[k * NT + t];
        out[(size_t)gph * NT + t] = a3;
    }
}

extern "C" void kernel_launch(void* const* d_in, const int* in_sizes, int n_in,
                              void* d_out, int out_size, void* d_ws, size_t ws_size,
                              hipStream_t stream)
{
    const float* atom_fea = (const float*)d_in[0];
    const float* nbr_fea  = (const float*)d_in[1];
    const int*   nbr_idx  = (const int*)d_in[2];
    const int*   bm       = (const int*)d_in[3];
    const float* emb_w    = (const float*)d_in[4];
    const float* emb_b    = (const float*)d_in[5];
    const float* emb_ln_g = (const float*)d_in[6];
    const float* emb_ln_b = (const float*)d_in[7];
    const float* edge_w   = (const float*)d_in[8];
    const float* edge_b   = (const float*)d_in[9];
    const float* conv_w1  = (const float*)d_in[10];
    const float* conv_b1  = (const float*)d_in[11];
    const float* conv_w2  = (const float*)d_in[12];
    const float* conv_b2  = (const float*)d_in[13];
    const float* ln_g     = (const float*)d_in[14];
    const float* ln_b     = (const float*)d_in[15];
    const float* out_w1   = (const float*)d_in[16];
    const float* out_b1   = (const float*)d_in[17];
    const float* out_w2   = (const float*)d_in[18];
    const float* out_b2   = (const float*)d_in[19];
    const float* out_w3   = (const float*)d_in[20];
    const float* out_b3   = (const float*)d_in[21];
    float* out = (float*)d_out;

    // ---- workspace layout (256B-aligned regions) ----
    char* base = (char*)d_ws;
    size_t off = 0;
    auto alloc = [&](size_t bytes) -> char* {
        char* p = base + off;
        off = (off + bytes + 255) & ~(size_t)255;
        return p;
    };
    float*  xbuf    = (float*) alloc((size_t)N_NODES * HD * 4);
    float*  aggr    = (float*) alloc((size_t)N_NODES * HD * 4);
    float*  cnt     = (float*) alloc((size_t)N_NODES * 4);
    float*  crystal = (float*) alloc((size_t)N_GRAPHS * HD * 4);
    float*  gcnt    = (float*) alloc((size_t)N_GRAPHS * 4);
    ushort* x_bf    = (ushort*)alloc((size_t)N_NODES * HD * 2);
    ushort* e_bf    = (ushort*)alloc((size_t)N_EDGES * HD * 2);
    ushort* w1s     = (ushort*)alloc((size_t)NLAYERS * 65536 * 2);
    ushort* w2s     = (ushort*)alloc((size_t)NLAYERS * 32768 * 2);

    // weights -> swizzled bf16
    k_swz_w1<<<(NLAYERS * 65536) / 256, 256, 0, stream>>>(conv_w1, w1s);
    k_swz_w2<<<(NLAYERS * 32768) / 256, 256, 0, stream>>>(conv_w2, w2s);

    // zero cnt + crystal + gcnt (contiguous region)
    int zn = N_NODES + N_GRAPHS * HD + N_GRAPHS + 128;
    k_zero<<<(zn + 255) / 256, 256, 0, stream>>>(cnt, zn);

    k_node_embed<<<N_NODES, 128, 0, stream>>>(atom_fea, emb_w, emb_b, emb_ln_g, emb_ln_b, xbuf, x_bf);
    k_edge_embed<<<N_EDGES / ETILE, 128, 0, stream>>>(nbr_fea, edge_w, edge_b, e_bf);
    k_count<<<N_EDGES / 256, 256, 0, stream>>>(nbr_idx, cnt);
    k_gcount<<<(N_NODES + 255) / 256, 256, 0, stream>>>(bm, gcnt);

    for (int l = 0; l < NLAYERS; ++l) {
        k_zero<<<(N_NODES * HD) / 256, 256, 0, stream>>>(aggr, N_NODES * HD);
        k_conv_mfma<<<N_EDGES / 64, 256, 0, stream>>>(
            x_bf, e_bf, nbr_idx,
            w1s + (size_t)l * 65536, conv_b1 + (size_t)l * 256,
            w2s + (size_t)l * 32768, conv_b2 + (size_t)l * 128,
            aggr);
        k_post<<<N_NODES, 128, 0, stream>>>(aggr, cnt, ln_g + (size_t)l * HD, ln_b + (size_t)l * HD, xbuf, x_bf);
    }

    k_gaggr<<<N_NODES, 128, 0, stream>>>(xbuf, bm, crystal);
    k_readout<<<N_GRAPHS, 128, 0, stream>>>(crystal, gcnt, out_w1, out_b1, out_w2, out_b2, out_w3, out_b3, out);
}

// Round 8
// 2753.273 us; speedup vs baseline: 1.7650x; 1.0146x over previous
//
#include <hip/hip_runtime.h>
#include <hip/hip_bf16.h>
#include <math.h>

#define N_NODES 50000
#define N_EDGES 800000
#define N_GRAPHS 1024
#define HD 128
#define NLAYERS 5
#define EDGE_IN 41
#define NT 3
#define LN_EPS 1e-5f

typedef unsigned int uint;
typedef unsigned short ushort;
typedef __attribute__((ext_vector_type(8))) short short8;
typedef __attribute__((ext_vector_type(4))) float f32x4;

// fast silu: x * rcp(1+exp(-x)); v_rcp_f32 rel err ~1e-7 (vs 6.8e-4 threshold)
__device__ __forceinline__ float silu_f(float v) {
    return v * __builtin_amdgcn_rcpf(1.0f + __expf(-v));
}

// round-to-nearest-even f32 -> bf16 bits
__device__ __forceinline__ ushort f2bf(float f) {
    uint u = __float_as_uint(f);
    u = u + 0x7FFFu + ((u >> 16) & 1u);
    return (ushort)(u >> 16);
}

__device__ __forceinline__ short8 ld16(const ushort* p) {
    union { int4 i; short8 s; } u;
    u.i = *(const int4*)p;
    return u.s;
}

__device__ __forceinline__ f32x4 mfma16(short8 a, short8 b, f32x4 c) {
    return __builtin_amdgcn_mfma_f32_16x16x32_bf16(a, b, c, 0, 0, 0);
}

// wave-local LDS fence
__device__ __forceinline__ void wave_lds_fence() {
    __asm__ volatile("s_waitcnt lgkmcnt(0)" ::: "memory");
}

// async global->LDS, 16 B per lane; HW writes lane's data to ldsbase + lane*16
__device__ __forceinline__ void cp16(const ushort* g, ushort* l) {
    __builtin_amdgcn_global_load_lds(
        (const __attribute__((address_space(1))) unsigned int*)g,
        (__attribute__((address_space(3))) unsigned int*)l, 16, 0, 0);
}

// stage 4096 ushorts (8 KB): wave w covers [w*1024, +1024), lane-contig 16 B
__device__ __forceinline__ void stage4k(ushort* lds, const ushort* g, int w, int L) {
#pragma unroll
    for (int i = 0; i < 2; ++i) {
        int f = w * 1024 + i * 512;
        cp16(g + f + L * 8, lds + f);
    }
}

// ---------------- zero ----------------
__global__ void k_zero(float* __restrict__ p, int n) {
    int i = blockIdx.x * 256 + threadIdx.x;
    if (i < n) p[i] = 0.0f;
}

// ---------------- weight swizzle: 16x16x32 B-fragment order ----------------
// w1s idx = ((c*8 + s)*64 + L)*8 + j  <-  W1[k = 32s + (L>>4)*8 + j][n = 16c + (L&15)]
__global__ void k_swz_w1(const float* __restrict__ w1, ushort* __restrict__ w1s) {
    int i = blockIdx.x * 256 + threadIdx.x;            // 5 * 65536
    int l = i >> 16;
    int r = i & 65535;
    int j = r & 7, L = (r >> 3) & 63, s = (r >> 9) & 7, c = (r >> 12) & 15;
    int k = 32 * s + ((L >> 4) & 3) * 8 + j;
    int n = 16 * c + (L & 15);
    w1s[i] = f2bf(w1[(size_t)l * 65536 + k * 256 + n]);
}
// w2s idx = ((s2*8 + t)*64 + L)*8 + j  <-  W2[k = 32*s2 + (L>>4)*8 + j][n = 16t + (L&15)]
__global__ void k_swz_w2(const float* __restrict__ w2, ushort* __restrict__ w2s) {
    int i = blockIdx.x * 256 + threadIdx.x;            // 5 * 32768
    int l = i >> 15;
    int r = i & 32767;
    int j = r & 7, L = (r >> 3) & 63, t = (r >> 9) & 7, s2 = (r >> 12) & 7;
    int k = 32 * s2 + ((L >> 4) & 3) * 8 + j;
    int n = 16 * t + (L & 15);
    w2s[i] = f2bf(w2[(size_t)l * 32768 + k * 128 + n]);
}

// ---------------- node embed: x = silu(LN(atom @ emb_w + emb_b)) ----------------
__global__ __launch_bounds__(128) void k_node_embed(
    const float* __restrict__ atom, const float* __restrict__ w,
    const float* __restrict__ b, const float* __restrict__ g,
    const float* __restrict__ bet, float* __restrict__ x, ushort* __restrict__ x_bf)
{
    int node = blockIdx.x;
    int h = threadIdx.x;
    float4 a = *(const float4*)(atom + (size_t)node * 4);
    float acc = b[h] + a.x * w[h] + a.y * w[HD + h] + a.z * w[2 * HD + h] + a.w * w[3 * HD + h];
    __shared__ float s1[2], s2[2];
    float sum = acc, sq = acc * acc;
    for (int off = 32; off > 0; off >>= 1) { sum += __shfl_down(sum, off); sq += __shfl_down(sq, off); }
    int wid = h >> 6, lane = h & 63;
    if (lane == 0) { s1[wid] = sum; s2[wid] = sq; }
    __syncthreads();
    float m = (s1[0] + s1[1]) * (1.0f / 128.0f);
    float v = (s2[0] + s2[1]) * (1.0f / 128.0f) - m * m;
    float y = (acc - m) * rsqrtf(v + LN_EPS) * g[h] + bet[h];
    y = silu_f(y);
    x[(size_t)node * HD + h] = y;
    x_bf[(size_t)node * HD + h] = f2bf(y);
}

// ---------------- edge embed -> bf16 ----------------
#define ETILE 32
__global__ __launch_bounds__(128) void k_edge_embed(
    const float* __restrict__ fea, const float* __restrict__ w,
    const float* __restrict__ b, ushort* __restrict__ e_bf)
{
    __shared__ float sf[ETILE][EDGE_IN + 1];
    int e0 = blockIdx.x * ETILE;
    int tid = threadIdx.x;
    for (int i = tid; i < ETILE * EDGE_IN; i += 128) {
        int m = i / EDGE_IN, k = i % EDGE_IN;
        sf[m][k] = fea[(size_t)(e0 + m) * EDGE_IN + k];
    }
    __syncthreads();
    float bb = b[tid];
    float acc[ETILE];
#pragma unroll
    for (int m = 0; m < ETILE; m++) acc[m] = bb;
    for (int k = 0; k < EDGE_IN; k++) {
        float wk = w[k * HD + tid];
#pragma unroll
        for (int m = 0; m < ETILE; m++) acc[m] += sf[m][k] * wk;
    }
#pragma unroll
    for (int m = 0; m < ETILE; m++)
        e_bf[(size_t)(e0 + m) * HD + tid] = f2bf(silu_f(acc[m]));
}

// ---------------- degree / graph counts ----------------
__global__ void k_count(const int* __restrict__ nbr_idx, float* __restrict__ cnt) {
    int i = blockIdx.x * 256 + threadIdx.x;
    if (i < N_EDGES) atomicAdd(&cnt[nbr_idx[2 * i + 1]], 1.0f);
}
__global__ void k_gcount(const int* __restrict__ bm, float* __restrict__ gcnt) {
    int i = blockIdx.x * 256 + threadIdx.x;
    if (i < N_NODES) atomicAdd(&gcnt[bm[i]], 1.0f);
}

// ---------------- fused conv layer: M=32 edges/wave, B-frags shared 2x ----------------
// Block = 4 waves, 128 edges (32/wave as two 16-edge M-tiles). 16 passes:
//   W1 chunk (8 KB) double-buffered via global_load_lds (R7 pattern).
//   GEMM1: 8 B-frag ds_reads feed 16 MFMAs (2 M-tiles) -> silu -> bf16 m1
//   half-chunk (wave-private, 32 edges x 16 cols).
//   Odd passes: GEMM2 k-step: 8 W2 B-frag reads feed 16 MFMAs into acc2[2][8].
// LDS B-read traffic halves vs R7 (each read serves 2 M-tiles): 4.8 GB/dispatch.
#define M1CP 40
__global__ __launch_bounds__(256, 3) void k_conv_mfma(
    const ushort* __restrict__ x_bf, const ushort* __restrict__ e_bf,
    const int* __restrict__ nbr_idx,
    const ushort* __restrict__ w1s, const float* __restrict__ cb1,
    const ushort* __restrict__ w2s, const float* __restrict__ cb2,
    float* __restrict__ aggr)
{
    __shared__ __align__(16) ushort sW1[2][4096];
    __shared__ __align__(16) ushort sW2[2][4096];
    __shared__ __align__(16) ushort sM1[4][32 * M1CP];
    __shared__ int sDst[128];

    int tid = threadIdx.x;
    int w = tid >> 6;
    int L = tid & 63;
    int m = L & 15;          // row/col-in-tile selector
    int quad = L >> 4;       // 0..3
    int eb = blockIdx.x * 128;
    int ew = eb + w * 32;    // wave's 32 edges

    if (tid < 128) sDst[tid] = nbr_idx[2 * (eb + tid) + 1];

    // A-fragments loaded once: tile t edges ew + t*16 + m
    short8 af[2][8];
#pragma unroll
    for (int t = 0; t < 2; ++t) {
        int src = nbr_idx[2 * (ew + t * 16 + m)];
        const ushort* xr = x_bf + (size_t)src * HD + quad * 8;
        const ushort* er = e_bf + (size_t)(ew + t * 16 + m) * HD + quad * 8;
#pragma unroll
        for (int s = 0; s < 4; ++s) af[t][s] = ld16(xr + 32 * s);
#pragma unroll
        for (int s = 0; s < 4; ++s) af[t][4 + s] = ld16(er + 32 * s);
    }

    f32x4 acc2[2][8];
#pragma unroll
    for (int t = 0; t < 2; ++t)
#pragma unroll
        for (int tt = 0; tt < 8; ++tt)
#pragma unroll
            for (int r = 0; r < 4; ++r) acc2[t][tt][r] = 0.0f;

    ushort* sm = sM1[w];

    // prologue: stage pass-0 W1 chunk and s2=0 W2 chunk
    stage4k(sW1[0], w1s, w, L);
    stage4k(sW2[0], w2s, w, L);

    for (int p = 0; p < 16; ++p) {
        __syncthreads();   // drains vmcnt -> current buffers ready
        // prefetch (overlaps compute below)
        if (p < 15) stage4k(sW1[(p + 1) & 1], w1s + (p + 1) * 4096, w, L);
        if ((p & 1) && (p >> 1) < 7)
            stage4k(sW2[((p >> 1) + 1) & 1], w2s + ((p >> 1) + 1) * 4096, w, L);

        // ---- GEMM1: cols [p*16, +16), both M-tiles share each B-frag ----
        f32x4 p0, p1;
#pragma unroll
        for (int r = 0; r < 4; ++r) { p0[r] = 0.0f; p1[r] = 0.0f; }
        const ushort* wb = sW1[p & 1] + L * 8;
#pragma unroll
        for (int s = 0; s < 8; ++s) {
            short8 wv = ld16(wb + s * 512);
            p0 = mfma16(af[0][s], wv, p0);
            p1 = mfma16(af[1][s], wv, p1);
        }

        // ---- bias + silu -> bf16 half-chunk (col = (p&1)*16 + m) ----
        float bv = cb1[p * 16 + m];
        int hb = (p & 1) * 16;
#pragma unroll
        for (int r = 0; r < 4; ++r) {
            sm[(quad * 4 + r) * M1CP + hb + m]        = f2bf(silu_f(p0[r] + bv));
            sm[(16 + quad * 4 + r) * M1CP + hb + m]   = f2bf(silu_f(p1[r] + bv));
        }

        // ---- odd pass: GEMM2 k-step s2 = p>>1 over the 32-col chunk ----
        if (p & 1) {
            wave_lds_fence();   // m1 writes (this+prev pass) complete
            short8 a20 = ld16(sm + m * M1CP + quad * 8);
            short8 a21 = ld16(sm + (16 + m) * M1CP + quad * 8);
            const ushort* w2p = sW2[(p >> 1) & 1] + L * 8;
#pragma unroll
            for (int tt = 0; tt < 8; ++tt) {
                short8 bf = ld16(w2p + tt * 512);
                acc2[0][tt] = mfma16(a20, bf, acc2[0][tt]);
                acc2[1][tt] = mfma16(a21, bf, acc2[1][tt]);
            }
            wave_lds_fence();   // WAR: chunk halves reused next pass-pair
        }
    }

    // ---- epilogue: bias + silu + coalesced atomic scatter ----
#pragma unroll
    for (int t = 0; t < 2; ++t) {
#pragma unroll
        for (int tt = 0; tt < 8; ++tt) {
            float bv = cb2[tt * 16 + m];
#pragma unroll
            for (int r = 0; r < 4; ++r) {
                int dst = sDst[w * 32 + t * 16 + quad * 4 + r];
                atomicAdd(aggr + (size_t)dst * HD + tt * 16 + m,
                          silu_f(acc2[t][tt][r] + bv));
            }
        }
    }
}

// ---------------- post: x = LN(x + aggr/cnt); emit bf16; re-zero aggr ----------------
__global__ __launch_bounds__(128) void k_post(
    float* __restrict__ aggr, const float* __restrict__ cnt,
    const float* __restrict__ g, const float* __restrict__ bet,
    float* __restrict__ x, ushort* __restrict__ x_bf)
{
    int node = blockIdx.x;
    int h = threadIdx.x;
    float inv = __builtin_amdgcn_rcpf(fmaxf(cnt[node], 1.0f));
    float av = aggr[(size_t)node * HD + h];
    aggr[(size_t)node * HD + h] = 0.0f;          // ready for next layer's atomics
    float acc = x[(size_t)node * HD + h] + av * inv;
    __shared__ float s1[2], s2[2];
    float sum = acc, sq = acc * acc;
    for (int off = 32; off > 0; off >>= 1) { sum += __shfl_down(sum, off); sq += __shfl_down(sq, off); }
    int wid = h >> 6, lane = h & 63;
    if (lane == 0) { s1[wid] = sum; s2[wid] = sq; }
    __syncthreads();
    float m = (s1[0] + s1[1]) * (1.0f / 128.0f);
    float v = (s2[0] + s2[1]) * (1.0f / 128.0f) - m * m;
    float y = (acc - m) * rsqrtf(v + LN_EPS) * g[h] + bet[h];
    x[(size_t)node * HD + h] = y;
    x_bf[(size_t)node * HD + h] = f2bf(y);
}

// ---------------- graph pooling ----------------
__global__ __launch_bounds__(128) void k_gaggr(
    const float* __restrict__ x, const int* __restrict__ bm,
    float* __restrict__ crystal)
{
    int node = blockIdx.x;
    int h = threadIdx.x;
    atomicAdd(&crystal[(size_t)bm[node] * HD + h], x[(size_t)node * HD + h]);
}

// ---------------- readout MLP ----------------
__global__ __launch_bounds__(128) void k_readout(
    const float* __restrict__ crystal, const float* __restrict__ gcnt,
    const float* __restrict__ w1, const float* __restrict__ b1,
    const float* __restrict__ w2, const float* __restrict__ b2,
    const float* __restrict__ w3, const float* __restrict__ b3,
    float* __restrict__ out)
{
    int gph = blockIdx.x;
    int t = threadIdx.x;
    __shared__ float sc[HD], sh1[HD], sh2[64];
    float inv = __builtin_amdgcn_rcpf(fmaxf(gcnt[gph], 1.0f));
    sc[t] = crystal[(size_t)gph * HD + t] * inv;
    __syncthreads();
    float acc = b1[t];
    for (int k = 0; k < HD; k++) acc += sc[k] * w1[k * HD + t];
    sh1[t] = silu_f(acc);
    __syncthreads();
    if (t < 64) {
        float a2 = b2[t];
        for (int k = 0; k < HD; k++) a2 += sh1[k] * w2[k * 64 + t];
        sh2[t] = silu_f(a2);
    }
    __syncthreads();
    if (t < NT) {
        float a3 = b3[t];
        for (int k = 0; k < 64; k++) a3 += sh2[k] * w3[k * NT + t];
        out[(size_t)gph * NT + t] = a3;
    }
}

extern "C" void kernel_launch(void* const* d_in, const int* in_sizes, int n_in,
                              void* d_out, int out_size, void* d_ws, size_t ws_size,
                              hipStream_t stream)
{
    const float* atom_fea = (const float*)d_in[0];
    const float* nbr_fea  = (const float*)d_in[1];
    const int*   nbr_idx  = (const int*)d_in[2];
    const int*   bm       = (const int*)d_in[3];
    const float* emb_w    = (const float*)d_in[4];
    const float* emb_b    = (const float*)d_in[5];
    const float* emb_ln_g = (const float*)d_in[6];
    const float* emb_ln_b = (const float*)d_in[7];
    const float* edge_w   = (const float*)d_in[8];
    const float* edge_b   = (const float*)d_in[9];
    const float* conv_w1  = (const float*)d_in[10];
    const float* conv_b1  = (const float*)d_in[11];
    const float* conv_w2  = (const float*)d_in[12];
    const float* conv_b2  = (const float*)d_in[13];
    const float* ln_g     = (const float*)d_in[14];
    const float* ln_b     = (const float*)d_in[15];
    const float* out_w1   = (const float*)d_in[16];
    const float* out_b1   = (const float*)d_in[17];
    const float* out_w2   = (const float*)d_in[18];
    const float* out_b2   = (const float*)d_in[19];
    const float* out_w3   = (const float*)d_in[20];
    const float* out_b3   = (const float*)d_in[21];
    float* out = (float*)d_out;

    // ---- workspace layout (256B-aligned regions) ----
    char* base = (char*)d_ws;
    size_t off = 0;
    auto alloc = [&](size_t bytes) -> char* {
        char* p = base + off;
        off = (off + bytes + 255) & ~(size_t)255;
        return p;
    };
    float*  xbuf    = (float*) alloc((size_t)N_NODES * HD * 4);
    float*  aggr    = (float*) alloc((size_t)N_NODES * HD * 4);
    float*  cnt     = (float*) alloc((size_t)N_NODES * 4);
    float*  crystal = (float*) alloc((size_t)N_GRAPHS * HD * 4);
    float*  gcnt    = (float*) alloc((size_t)N_GRAPHS * 4);
    ushort* x_bf    = (ushort*)alloc((size_t)N_NODES * HD * 2);
    ushort* e_bf    = (ushort*)alloc((size_t)N_EDGES * HD * 2);
    ushort* w1s     = (ushort*)alloc((size_t)NLAYERS * 65536 * 2);
    ushort* w2s     = (ushort*)alloc((size_t)NLAYERS * 32768 * 2);

    // weights -> swizzled bf16
    k_swz_w1<<<(NLAYERS * 65536) / 256, 256, 0, stream>>>(conv_w1, w1s);
    k_swz_w2<<<(NLAYERS * 32768) / 256, 256, 0, stream>>>(conv_w2, w2s);

    // zero aggr (layer 0 only; k_post re-zeroes for later layers)
    k_zero<<<(N_NODES * HD) / 256, 256, 0, stream>>>(aggr, N_NODES * HD);
    // zero cnt + crystal + gcnt (contiguous region)
    int zn = N_NODES + N_GRAPHS * HD + N_GRAPHS + 128;
    k_zero<<<(zn + 255) / 256, 256, 0, stream>>>(cnt, zn);

    k_node_embed<<<N_NODES, 128, 0, stream>>>(atom_fea, emb_w, emb_b, emb_ln_g, emb_ln_b, xbuf, x_bf);
    k_edge_embed<<<N_EDGES / ETILE, 128, 0, stream>>>(nbr_fea, edge_w, edge_b, e_bf);
    k_count<<<N_EDGES / 256, 256, 0, stream>>>(nbr_idx, cnt);
    k_gcount<<<(N_NODES + 255) / 256, 256, 0, stream>>>(bm, gcnt);

    for (int l = 0; l < NLAYERS; ++l) {
        k_conv_mfma<<<N_EDGES / 128, 256, 0, stream>>>(
            x_bf, e_bf, nbr_idx,
            w1s + (size_t)l * 65536, conv_b1 + (size_t)l * 256,
            w2s + (size_t)l * 32768, conv_b2 + (size_t)l * 128,
            aggr);
        k_post<<<N_NODES, 128, 0, stream>>>(aggr, cnt, ln_g + (size_t)l * HD, ln_b + (size_t)l * HD, xbuf, x_bf);
    }

    k_gaggr<<<N_NODES, 128, 0, stream>>>(xbuf, bm, crystal);
    k_readout<<<N_GRAPHS, 128, 0, stream>>>(crystal, gcnt, out_w1, out_b1, out_w2, out_b2, out_w3, out_b3, out);
}